// Round 1
// baseline (477.510 us; speedup 1.0000x reference)
//
#include <hip/hip_runtime.h>
#include <hip/hip_bf16.h>
#include <stdint.h>

// LoRA int8-dequant linear, MI355X/gfx950.
// Strategy: concat LoRA rank-64 into the K dimension of one bf16 MFMA GEMM.
//   Xcat[8192][4160] = [ bf16(x) | bf16(x @ A^T) ]
//   Wcat[4096][4160] = [ bf16(q*scale) | bf16(2*B) ]
//   out = Xcat @ Wcat^T   (fp32 out, fp32 accum)
// Workspace: Xcat 68.2MB + Wcat 34.1MB + Abf 0.5MB = ~102.8 MB.

typedef __bf16 bf16x8 __attribute__((ext_vector_type(8)));
typedef float f32x4 __attribute__((ext_vector_type(4)));

#define DIN  4096
#define DOUT 4096
#define MTOT 8192
#define RNK  64
#define LDK  4160  // DIN + RNK, divisible by 64

__device__ inline void gload_lds16(const void* g, void* l) {
  __builtin_amdgcn_global_load_lds((const __attribute__((address_space(1))) void*)g,
                                   (__attribute__((address_space(3))) void*)l,
                                   16, 0, 0);
}

// ---- x (fp32) -> Xcat[:, 0:4096] bf16 ----
__global__ void cvt_x_kernel(const float* __restrict__ x, __bf16* __restrict__ Xcat) {
  int i = blockIdx.x * blockDim.x + threadIdx.x;  // MTOT*DIN/4 threads
  int row = i >> 10;
  int c4 = (i & 1023) << 2;
  float4 v = *(const float4*)(x + (size_t)row * DIN + c4);
  union { __bf16 h[4]; uint64_t u; } p;
  p.h[0] = (__bf16)v.x; p.h[1] = (__bf16)v.y;
  p.h[2] = (__bf16)v.z; p.h[3] = (__bf16)v.w;
  *(uint64_t*)(Xcat + (size_t)row * LDK + c4) = p.u;
}

// ---- qweight (int32 codes) * scale[row] -> Wcat[:, 0:4096] bf16 ----
__global__ void cvt_w_kernel(const int* __restrict__ q, const float* __restrict__ scale,
                             __bf16* __restrict__ Wcat) {
  int i = blockIdx.x * blockDim.x + threadIdx.x;  // DOUT*DIN/4 threads
  int row = i >> 10;
  int c4 = (i & 1023) << 2;
  int4 v = *(const int4*)(q + (size_t)row * DIN + c4);
  float s = scale[row];
  union { __bf16 h[4]; uint64_t u; } p;
  p.h[0] = (__bf16)((float)v.x * s); p.h[1] = (__bf16)((float)v.y * s);
  p.h[2] = (__bf16)((float)v.z * s); p.h[3] = (__bf16)((float)v.w * s);
  *(uint64_t*)(Wcat + (size_t)row * LDK + c4) = p.u;
}

// ---- lora_A -> Abf (bf16, compact [64][4096]); 2*lora_B -> Wcat[:, 4096:4160] ----
__global__ void cvt_ab_kernel(const float* __restrict__ A, const float* __restrict__ B,
                              __bf16* __restrict__ Abf, __bf16* __restrict__ Wcat) {
  int i = blockIdx.x * blockDim.x + threadIdx.x;  // 64*4096/4 = 65536 threads
  {
    int row = i >> 10;
    int c4 = (i & 1023) << 2;
    float4 v = *(const float4*)(A + (size_t)row * DIN + c4);
    union { __bf16 h[4]; uint64_t u; } p;
    p.h[0] = (__bf16)v.x; p.h[1] = (__bf16)v.y;
    p.h[2] = (__bf16)v.z; p.h[3] = (__bf16)v.w;
    *(uint64_t*)(Abf + (size_t)row * DIN + c4) = p.u;
  }
  {
    int row = i >> 4;          // 0..4095
    int r4 = (i & 15) << 2;    // 0..60
    float4 v = *(const float4*)(B + (size_t)row * RNK + r4);
    union { __bf16 h[4]; uint64_t u; } p;
    p.h[0] = (__bf16)(2.0f * v.x); p.h[1] = (__bf16)(2.0f * v.y);
    p.h[2] = (__bf16)(2.0f * v.z); p.h[3] = (__bf16)(2.0f * v.w);
    *(uint64_t*)(Wcat + (size_t)row * LDK + DIN + r4) = p.u;
  }
}

// ---- xa = Xcat[:, :4096] @ Abf^T -> bf16 -> Xcat[:, 4096:4160] ----
// 128 threads = 2 waves; each wave: 16 rows x 64 cols, K-loop over 4096.
__global__ __launch_bounds__(128) void lora_xa_kernel(const __bf16* __restrict__ Abf,
                                                      __bf16* Xcat) {
  int wid = threadIdx.x >> 6, lane = threadIdx.x & 63;
  int rowbase = blockIdx.x * 32 + wid * 16;
  f32x4 acc[4] = {};
  const __bf16* xrow = Xcat + (size_t)(rowbase + (lane & 15)) * LDK + ((lane >> 4) * 8);
  for (int k0 = 0; k0 < DIN; k0 += 32) {
    bf16x8 af = *(const bf16x8*)(xrow + k0);
#pragma unroll
    for (int ni = 0; ni < 4; ++ni) {
      bf16x8 bfv = *(const bf16x8*)(Abf + (size_t)(ni * 16 + (lane & 15)) * DIN + k0 + (lane >> 4) * 8);
      acc[ni] = __builtin_amdgcn_mfma_f32_16x16x32_bf16(af, bfv, acc[ni], 0, 0, 0);
    }
  }
#pragma unroll
  for (int ni = 0; ni < 4; ++ni) {
#pragma unroll
    for (int j = 0; j < 4; ++j) {
      int row = rowbase + (lane >> 4) * 4 + j;
      int col = ni * 16 + (lane & 15);
      Xcat[(size_t)row * LDK + DIN + col] = (__bf16)acc[ni][j];
    }
  }
}

// ---- main GEMM: out[M][N] = Xcat @ Wcat^T, 128x128 tile, BK=64, 4 waves ----
__global__ __launch_bounds__(256) void gemm_main_kernel(const __bf16* __restrict__ Xc,
                                                        const __bf16* __restrict__ Wc,
                                                        float* __restrict__ out) {
  __shared__ __bf16 As[128 * 64];
  __shared__ __bf16 Bs[128 * 64];
  const int tid = threadIdx.x;
  const int lane = tid & 63;
  const int wid = tid >> 6;
  const int wr = wid >> 1, wc = wid & 1;  // 2x2 wave grid, 64x64 each
  const int bm = blockIdx.y * 128, bn = blockIdx.x * 128;

  const __bf16* gA = Xc + (size_t)bm * LDK;
  const __bf16* gB = Wc + (size_t)bn * LDK;
  const int srow = tid >> 3;        // 0..31
  const int scol = (tid & 7) * 8;   // 0,8,...,56

  f32x4 acc[4][4] = {};

  for (int kt = 0; kt < LDK / 64; ++kt) {
    const int k0 = kt * 64;
#pragma unroll
    for (int s = 0; s < 4; ++s)
      gload_lds16(gA + (size_t)(s * 32 + srow) * LDK + k0 + scol, &As[s * 2048 + tid * 8]);
#pragma unroll
    for (int s = 0; s < 4; ++s)
      gload_lds16(gB + (size_t)(s * 32 + srow) * LDK + k0 + scol, &Bs[s * 2048 + tid * 8]);
    __syncthreads();  // compiler drains vmcnt before s_barrier -> LDS ready
#pragma unroll
    for (int ks = 0; ks < 2; ++ks) {
      bf16x8 af[4], bfv[4];
#pragma unroll
      for (int mi = 0; mi < 4; ++mi)
        af[mi] = *(const bf16x8*)&As[(wr * 64 + mi * 16 + (lane & 15)) * 64 + ks * 32 + (lane >> 4) * 8];
#pragma unroll
      for (int ni = 0; ni < 4; ++ni)
        bfv[ni] = *(const bf16x8*)&Bs[(wc * 64 + ni * 16 + (lane & 15)) * 64 + ks * 32 + (lane >> 4) * 8];
#pragma unroll
      for (int mi = 0; mi < 4; ++mi)
#pragma unroll
        for (int ni = 0; ni < 4; ++ni)
          acc[mi][ni] = __builtin_amdgcn_mfma_f32_16x16x32_bf16(af[mi], bfv[ni], acc[mi][ni], 0, 0, 0);
    }
    __syncthreads();  // protect LDS before next stage overwrites
  }

#pragma unroll
  for (int mi = 0; mi < 4; ++mi) {
#pragma unroll
    for (int ni = 0; ni < 4; ++ni) {
      int row = bm + wr * 64 + mi * 16 + (lane >> 4) * 4;
      int col = bn + wc * 64 + ni * 16 + (lane & 15);
#pragma unroll
      for (int j = 0; j < 4; ++j)
        out[(size_t)(row + j) * DOUT + col] = acc[mi][ni][j];
    }
  }
}

extern "C" void kernel_launch(void* const* d_in, const int* in_sizes, int n_in,
                              void* d_out, int out_size, void* d_ws, size_t ws_size,
                              hipStream_t stream) {
  const float* x = (const float*)d_in[0];
  const int* qw = (const int*)d_in[1];
  const float* scale = (const float*)d_in[2];
  const float* lA = (const float*)d_in[3];
  const float* lB = (const float*)d_in[4];
  float* out = (float*)d_out;

  char* ws = (char*)d_ws;
  __bf16* Xcat = (__bf16*)ws;                                               // 8192*4160*2
  __bf16* Wcat = (__bf16*)(ws + (size_t)MTOT * LDK * 2);                    // 4096*4160*2
  __bf16* Abf = (__bf16*)(ws + (size_t)MTOT * LDK * 2 + (size_t)DOUT * LDK * 2);  // 64*4096*2

  cvt_x_kernel<<<MTOT * (DIN / 4) / 256, 256, 0, stream>>>(x, Xcat);
  cvt_w_kernel<<<DOUT * (DIN / 4) / 256, 256, 0, stream>>>(qw, scale, Wcat);
  cvt_ab_kernel<<<RNK * (DIN / 4) / 256, 256, 0, stream>>>(lA, lB, Abf, Wcat);
  lora_xa_kernel<<<MTOT / 32, 128, 0, stream>>>(Abf, Xcat);
  gemm_main_kernel<<<dim3(DOUT / 128, MTOT / 128), 256, 0, stream>>>(Xcat, Wcat, out);
}

// Round 2
// 333.892 us; speedup vs baseline: 1.4301x; 1.4301x over previous
//
#include <hip/hip_runtime.h>
#include <hip/hip_bf16.h>
#include <stdint.h>

// LoRA int8-dequant linear, MI355X/gfx950.
//   Xcat[8192][4160] = [ bf16(x) | bf16(x @ A^T) ]
//   Wcat[4096][4160] = [ bf16(q*scale) | bf16(2*B) ]
//   out = Xcat @ Wcat^T   (fp32 out, fp32 accum)
// Main GEMM: 256x256 tile, BK=64, 8 waves, 8-phase-per-2-K-tiles schedule
// (T1 XCD swizzle + T2 LDS XOR swizzle + T3/T4 counted-vmcnt pipeline + T5 setprio).

typedef __bf16 bf16x8 __attribute__((ext_vector_type(8)));
typedef float f32x4 __attribute__((ext_vector_type(4)));

#define DIN   4096
#define DOUT  4096
#define MTOT  8192
#define RNK   64
#define LDK   4160          // DIN + RNK
#define PITCH 8320          // LDK * 2 bytes
#define NT    65            // K-tiles of 64

__device__ inline void gload_lds16(const void* g, void* l) {
  __builtin_amdgcn_global_load_lds((const __attribute__((address_space(1))) void*)g,
                                   (__attribute__((address_space(3))) void*)l,
                                   16, 0, 0);
}

// ---- x (fp32) -> Xcat[:, 0:4096] bf16 ----
__global__ void cvt_x_kernel(const float* __restrict__ x, __bf16* __restrict__ Xcat) {
  int i = blockIdx.x * blockDim.x + threadIdx.x;
  int row = i >> 10;
  int c4 = (i & 1023) << 2;
  float4 v = *(const float4*)(x + (size_t)row * DIN + c4);
  union { __bf16 h[4]; uint64_t u; } p;
  p.h[0] = (__bf16)v.x; p.h[1] = (__bf16)v.y;
  p.h[2] = (__bf16)v.z; p.h[3] = (__bf16)v.w;
  *(uint64_t*)(Xcat + (size_t)row * LDK + c4) = p.u;
}

// ---- qweight * scale[row] -> Wcat[:, 0:4096] bf16 ----
__global__ void cvt_w_kernel(const int* __restrict__ q, const float* __restrict__ scale,
                             __bf16* __restrict__ Wcat) {
  int i = blockIdx.x * blockDim.x + threadIdx.x;
  int row = i >> 10;
  int c4 = (i & 1023) << 2;
  int4 v = *(const int4*)(q + (size_t)row * DIN + c4);
  float s = scale[row];
  union { __bf16 h[4]; uint64_t u; } p;
  p.h[0] = (__bf16)((float)v.x * s); p.h[1] = (__bf16)((float)v.y * s);
  p.h[2] = (__bf16)((float)v.z * s); p.h[3] = (__bf16)((float)v.w * s);
  *(uint64_t*)(Wcat + (size_t)row * LDK + c4) = p.u;
}

// ---- lora_A -> Abf; 2*lora_B -> Wcat[:, 4096:4160] ----
__global__ void cvt_ab_kernel(const float* __restrict__ A, const float* __restrict__ B,
                              __bf16* __restrict__ Abf, __bf16* __restrict__ Wcat) {
  int i = blockIdx.x * blockDim.x + threadIdx.x;
  {
    int row = i >> 10;
    int c4 = (i & 1023) << 2;
    float4 v = *(const float4*)(A + (size_t)row * DIN + c4);
    union { __bf16 h[4]; uint64_t u; } p;
    p.h[0] = (__bf16)v.x; p.h[1] = (__bf16)v.y;
    p.h[2] = (__bf16)v.z; p.h[3] = (__bf16)v.w;
    *(uint64_t*)(Abf + (size_t)row * DIN + c4) = p.u;
  }
  {
    int row = i >> 4;
    int r4 = (i & 15) << 2;
    float4 v = *(const float4*)(B + (size_t)row * RNK + r4);
    union { __bf16 h[4]; uint64_t u; } p;
    p.h[0] = (__bf16)(2.0f * v.x); p.h[1] = (__bf16)(2.0f * v.y);
    p.h[2] = (__bf16)(2.0f * v.z); p.h[3] = (__bf16)(2.0f * v.w);
    *(uint64_t*)(Wcat + (size_t)row * LDK + DIN + r4) = p.u;
  }
}

// ---- xa = Xcat[:, :4096] @ Abf^T -> bf16 -> Xcat[:, 4096:4160] ----
__global__ __launch_bounds__(128) void lora_xa_kernel(const __bf16* __restrict__ Abf,
                                                      __bf16* Xcat) {
  int wid = threadIdx.x >> 6, lane = threadIdx.x & 63;
  int rowbase = blockIdx.x * 32 + wid * 16;
  f32x4 acc[4] = {};
  const __bf16* xrow = Xcat + (size_t)(rowbase + (lane & 15)) * LDK + ((lane >> 4) * 8);
  for (int k0 = 0; k0 < DIN; k0 += 32) {
    bf16x8 af = *(const bf16x8*)(xrow + k0);
#pragma unroll
    for (int ni = 0; ni < 4; ++ni) {
      bf16x8 bfv = *(const bf16x8*)(Abf + (size_t)(ni * 16 + (lane & 15)) * DIN + k0 + (lane >> 4) * 8);
      acc[ni] = __builtin_amdgcn_mfma_f32_16x16x32_bf16(af, bfv, acc[ni], 0, 0, 0);
    }
  }
#pragma unroll
  for (int ni = 0; ni < 4; ++ni)
#pragma unroll
    for (int j = 0; j < 4; ++j) {
      int row = rowbase + (lane >> 4) * 4 + j;
      int col = ni * 16 + (lane & 15);
      Xcat[(size_t)row * LDK + DIN + col] = (__bf16)acc[ni][j];
    }
}

// ==== main GEMM: 256x256 tile, 8 waves, 4-phase/K-tile counted-vmcnt pipeline ====
// LDS (128 KiB dynamic): buf[2] x { A-half0, A-half1, B-half0, B-half1 } x 16 KiB.
// Half = 128 rows x 64 cols bf16, row r at bytes r*128 + (c ^ ((r&7)<<4))  [T2 swizzle].
// Staged linearly by global_load_lds with inverse-swizzled per-lane SOURCE (rule #21).
// Per K-tile kt (buffer cur=kt&1):
//   ph0: ds_read A-lo(8) + all B(8); stage A1 of kt+1 -> buf[cur^1]; MFMA mi0-3 x ni0-1
//   ph1: stage B1 of kt+2 -> buf[cur];                               MFMA mi0-3 x ni2-3
//   ph2: ds_read A-hi(8);  stage B0 of kt+2 -> buf[cur];             MFMA mi4-7 x ni2-3
//   ph3: stage A0 of kt+2 -> buf[cur]; MFMA mi4-7 x ni0-1; vmcnt(6)
// Slot-safety: every stage is issued after a barrier that follows the old data's
// last ds_read (B slots last read ph0, A-lo ph0, A-hi ph2) -> race-free by
// construction, loads never drained (vmcnt(6) = 3 half-tiles in flight).
__global__ __launch_bounds__(512, 2) void gemm8_kernel(const __bf16* __restrict__ Xc,
                                                       const __bf16* __restrict__ Wc,
                                                       float* __restrict__ out) {
  extern __shared__ char smem[];
  const int tid = threadIdx.x;
  const int lane = tid & 63;
  const int w = tid >> 6;        // wave 0..7
  const int wr = w >> 2;         // 0..1 -> rows wr*128
  const int wc = w & 3;          // 0..3 -> cols wc*64

  // bijective XCD swizzle (nwg=512, 512%8==0)
  const int swz = (blockIdx.x & 7) * 64 + (blockIdx.x >> 3);
  const int bx = swz & 15;       // N tile 0..15
  const int by = swz >> 4;       // M tile 0..31
  const size_t bm = (size_t)by * 256, bn = (size_t)bx * 256;

  const char* Ab = (const char*)Xc;
  const char* Bb = (const char*)Wc;

  // staging lane constants: lane covers local row (chunk*8 + lane>>3), 16B col (lane&7)
  const int sl_row = lane >> 3;
  const int sl_col = 16 * ((lane & 7) ^ (lane >> 3));   // inverse-swizzled source col

  // read-side swizzled col byte offsets for ks=0/1 (row&7 == lane&7 for all frags)
  const int cx0 = (((lane >> 4) << 4)) ^ ((lane & 7) << 4);
  const int cx1 = (64 | ((lane >> 4) << 4)) ^ ((lane & 7) << 4);

  auto STAGE = [&](int st, int buf, int isB, int h) {
    const char* gb = isB ? Bb : Ab;
    const size_t r0 = (isB ? bn : bm) + (size_t)h * 128;
    char* d0 = smem + buf * 65536 + isB * 32768 + h * 16384 + (w * 2) * 1024 + lane * 16;
#pragma unroll
    for (int s = 0; s < 2; ++s) {
      const int rl = (w * 2 + s) * 8 + sl_row;
      gload_lds16(gb + (r0 + rl) * PITCH + (size_t)st * 128 + sl_col, d0 + s * 1024);
    }
  };

  bf16x8 a[4][2], b[4][2];
  f32x4 acc[8][4] = {};

  // ---- prologue: tile0 fully, then tile1's {B1,B0,A0}; keep 3 halves in flight ----
  STAGE(0, 0, 0, 0); STAGE(0, 0, 0, 1); STAGE(0, 0, 1, 0); STAGE(0, 0, 1, 1);
  STAGE(1, 1, 1, 1); STAGE(1, 1, 1, 0); STAGE(1, 1, 0, 0);
  asm volatile("s_waitcnt vmcnt(6)" ::: "memory");
  __builtin_amdgcn_s_barrier();

  for (int kt = 0; kt < NT; ++kt) {
    const int cur = kt & 1;
    const int st1 = (kt + 1 < NT) ? kt + 1 : NT - 1;   // clamped dummy keeps vmcnt uniform
    const int st2 = (kt + 2 < NT) ? kt + 2 : NT - 1;
    const int abase = cur * 65536 + wr * 16384 + (lane & 15) * 128;
    const int bbase = cur * 65536 + 32768 + (wc >> 1) * 16384 + ((wc & 1) * 64 + (lane & 15)) * 128;

    // ---------- phase 0 ----------
#pragma unroll
    for (int mi = 0; mi < 4; ++mi) {
      a[mi][0] = *(const bf16x8*)(smem + abase + mi * 2048 + cx0);
      a[mi][1] = *(const bf16x8*)(smem + abase + mi * 2048 + cx1);
    }
#pragma unroll
    for (int ni = 0; ni < 4; ++ni) {
      b[ni][0] = *(const bf16x8*)(smem + bbase + ni * 2048 + cx0);
      b[ni][1] = *(const bf16x8*)(smem + bbase + ni * 2048 + cx1);
    }
    STAGE(st1, cur ^ 1, 0, 1);
    __builtin_amdgcn_s_barrier();
    asm volatile("s_waitcnt lgkmcnt(0)" ::: "memory");
    __builtin_amdgcn_sched_barrier(0);
    __builtin_amdgcn_s_setprio(1);
#pragma unroll
    for (int ks = 0; ks < 2; ++ks)
#pragma unroll
      for (int mi = 0; mi < 4; ++mi)
#pragma unroll
        for (int ni = 0; ni < 2; ++ni)
          acc[mi][ni] = __builtin_amdgcn_mfma_f32_16x16x32_bf16(a[mi][ks], b[ni][ks], acc[mi][ni], 0, 0, 0);
    __builtin_amdgcn_s_setprio(0);
    __builtin_amdgcn_sched_barrier(0);
    __builtin_amdgcn_s_barrier();

    // ---------- phase 1 ----------
    STAGE(st2, cur, 1, 1);
    __builtin_amdgcn_s_barrier();
    __builtin_amdgcn_s_setprio(1);
#pragma unroll
    for (int ks = 0; ks < 2; ++ks)
#pragma unroll
      for (int mi = 0; mi < 4; ++mi)
#pragma unroll
        for (int ni = 0; ni < 2; ++ni)
          acc[mi][2 + ni] = __builtin_amdgcn_mfma_f32_16x16x32_bf16(a[mi][ks], b[2 + ni][ks], acc[mi][2 + ni], 0, 0, 0);
    __builtin_amdgcn_s_setprio(0);
    __builtin_amdgcn_sched_barrier(0);
    __builtin_amdgcn_s_barrier();

    // ---------- phase 2 ----------
#pragma unroll
    for (int mi = 0; mi < 4; ++mi) {
      a[mi][0] = *(const bf16x8*)(smem + abase + 8192 + mi * 2048 + cx0);
      a[mi][1] = *(const bf16x8*)(smem + abase + 8192 + mi * 2048 + cx1);
    }
    STAGE(st2, cur, 1, 0);
    __builtin_amdgcn_s_barrier();
    asm volatile("s_waitcnt lgkmcnt(0)" ::: "memory");
    __builtin_amdgcn_sched_barrier(0);
    __builtin_amdgcn_s_setprio(1);
#pragma unroll
    for (int ks = 0; ks < 2; ++ks)
#pragma unroll
      for (int mi = 0; mi < 4; ++mi)
#pragma unroll
        for (int ni = 0; ni < 2; ++ni)
          acc[4 + mi][2 + ni] = __builtin_amdgcn_mfma_f32_16x16x32_bf16(a[mi][ks], b[2 + ni][ks], acc[4 + mi][2 + ni], 0, 0, 0);
    __builtin_amdgcn_s_setprio(0);
    __builtin_amdgcn_sched_barrier(0);
    __builtin_amdgcn_s_barrier();

    // ---------- phase 3 ----------
    STAGE(st2, cur, 0, 0);
    __builtin_amdgcn_s_barrier();
    __builtin_amdgcn_s_setprio(1);
#pragma unroll
    for (int ks = 0; ks < 2; ++ks)
#pragma unroll
      for (int mi = 0; mi < 4; ++mi)
#pragma unroll
        for (int ni = 0; ni < 2; ++ni)
          acc[4 + mi][ni] = __builtin_amdgcn_mfma_f32_16x16x32_bf16(a[mi][ks], b[ni][ks], acc[4 + mi][ni], 0, 0, 0);
    __builtin_amdgcn_s_setprio(0);
    __builtin_amdgcn_sched_barrier(0);
    asm volatile("s_waitcnt vmcnt(6)" ::: "memory");
    __builtin_amdgcn_s_barrier();
  }

  // ---- epilogue: C write ----
#pragma unroll
  for (int mi = 0; mi < 8; ++mi)
#pragma unroll
    for (int ni = 0; ni < 4; ++ni) {
      const size_t row = bm + wr * 128 + mi * 16 + (lane >> 4) * 4;
      const size_t col = bn + wc * 64 + ni * 16 + (lane & 15);
#pragma unroll
      for (int j = 0; j < 4; ++j)
        out[(row + j) * DOUT + col] = acc[mi][ni][j];
    }
}

extern "C" void kernel_launch(void* const* d_in, const int* in_sizes, int n_in,
                              void* d_out, int out_size, void* d_ws, size_t ws_size,
                              hipStream_t stream) {
  const float* x = (const float*)d_in[0];
  const int* qw = (const int*)d_in[1];
  const float* scale = (const float*)d_in[2];
  const float* lA = (const float*)d_in[3];
  const float* lB = (const float*)d_in[4];
  float* out = (float*)d_out;

  char* ws = (char*)d_ws;
  __bf16* Xcat = (__bf16*)ws;
  __bf16* Wcat = (__bf16*)(ws + (size_t)MTOT * LDK * 2);
  __bf16* Abf = (__bf16*)(ws + (size_t)MTOT * LDK * 2 + (size_t)DOUT * LDK * 2);

  hipFuncSetAttribute((const void*)gemm8_kernel,
                      hipFuncAttributeMaxDynamicSharedMemorySize, 131072);

  cvt_x_kernel<<<MTOT * (DIN / 4) / 256, 256, 0, stream>>>(x, Xcat);
  cvt_w_kernel<<<DOUT * (DIN / 4) / 256, 256, 0, stream>>>(qw, scale, Wcat);
  cvt_ab_kernel<<<RNK * (DIN / 4) / 256, 256, 0, stream>>>(lA, lB, Abf, Wcat);
  lora_xa_kernel<<<MTOT / 32, 128, 0, stream>>>(Abf, Xcat);
  gemm8_kernel<<<(MTOT / 256) * (DOUT / 256), 512, 131072, stream>>>(Xcat, Wcat, out);
}